// Round 5
// baseline (246.341 us; speedup 1.0000x reference)
//
#include <hip/hip_runtime.h>

#define B 8
#define N 2048
#define M 2048
#define DIN 256
#define E 128
#define ALPHA 0.01f

typedef __attribute__((ext_vector_type(8))) short bf16x8;
typedef __attribute__((ext_vector_type(4))) float f32x4;

__device__ inline ushort f2bf(float x) {
  unsigned u = __float_as_uint(x);
  u = (u + 0x7FFFu + ((u >> 16) & 1u)) >> 16;  // RNE
  return (ushort)u;
}

__device__ inline float leaky_mask(float a1r, float a2, float mk) {
  float s = a1r + a2;
  s = s > 0.f ? s : ALPHA * s;
  return s + mk;
}

// ---------------------------------------------------------------------------
// K0: v1[k] = sum_e W1[k][e]*a1[e], v2[k] = sum_e W1[k][e]*a1[128+e]
// ---------------------------------------------------------------------------
__global__ __launch_bounds__(256) void prep_v_kernel(
    const float* __restrict__ W1, const float* __restrict__ a1,
    float* __restrict__ v1, float* __restrict__ v2) {
  int k = threadIdx.x;
  float s1 = 0.f, s2 = 0.f;
#pragma unroll 8
  for (int e = 0; e < E; ++e) {
    float w = W1[k * E + e];
    s1 += w * a1[e];
    s2 += w * a1[E + e];
  }
  v1[k] = s1;
  v2[k] = s2;
}

// ---------------------------------------------------------------------------
// K1: att1[row] = dot(input1[row,:], v1); att2 likewise. One wave per row.
// ---------------------------------------------------------------------------
__global__ __launch_bounds__(256) void att_kernel(
    const float* __restrict__ in1, const float* __restrict__ in2,
    const float* __restrict__ v1, const float* __restrict__ v2,
    float* __restrict__ att1, float* __restrict__ att2) {
  int wave = blockIdx.x * 4 + (threadIdx.x >> 6);
  int lane = threadIdx.x & 63;
  const float* src;
  const float* v;
  float* dst;
  int row;
  if (wave < B * N) {
    src = in1; v = v1; dst = att1; row = wave;
  } else {
    src = in2; v = v2; dst = att2; row = wave - B * N;
  }
  float4 x = *(const float4*)(src + (size_t)row * DIN + lane * 4);
  float4 vv = *(const float4*)(v + lane * 4);
  float d = x.x * vv.x + x.y * vv.y + x.z * vv.z + x.w * vv.w;
#pragma unroll
  for (int off = 32; off; off >>= 1) d += __shfl_down(d, off, 64);
  if (lane == 0) dst[row] = d;
}

// ---------------------------------------------------------------------------
// K2: Wh2 = input2 @ W1, fp32 compute, epilogue packs bf16 into
// MFMA-B-fragment layout: Wb[(m>>3)*1024 + e*8 + (m&7)].
// ---------------------------------------------------------------------------
__global__ __launch_bounds__(256) void wh2_kernel(
    const float* __restrict__ in2, const float* __restrict__ W1,
    ushort* __restrict__ Wb) {
  __shared__ float a[32][DIN];  // 32 KB
  int r0 = blockIdx.x * 32;
#pragma unroll
  for (int i = 0; i < 8; ++i) {
    int f = (threadIdx.x + i * 256) * 4;
    int r = f >> 8, k = f & 255;
    *(float4*)&a[r][k] = *(const float4*)(in2 + (size_t)(r0 + r) * DIN + k);
  }
  __syncthreads();
  int c  = (threadIdx.x & 31) * 4;
  int tr = (threadIdx.x >> 5) * 4;
  float acc[4][4] = {};
  for (int k = 0; k < DIN; ++k) {
    float4 b = *(const float4*)(W1 + k * E + c);
#pragma unroll
    for (int r = 0; r < 4; ++r) {
      float av = a[tr + r][k];
      acc[r][0] += av * b.x;
      acc[r][1] += av * b.y;
      acc[r][2] += av * b.z;
      acc[r][3] += av * b.w;
    }
  }
#pragma unroll
  for (int r = 0; r < 4; ++r) {
    int m = r0 + tr + r;
    size_t gbase = (size_t)(m >> 3) * 128 * 8 + (m & 7);
#pragma unroll
    for (int j = 0; j < 4; ++j)
      Wb[gbase + (size_t)(c + j) * 8] = f2bf(acc[r][j]);
  }
}

// ---------------------------------------------------------------------------
// K3: per-row softmax stats. One wave per row, no LDS, global reads L1-hot.
// ---------------------------------------------------------------------------
__global__ __launch_bounds__(256) void stats_kernel(
    const float* __restrict__ att1, const float* __restrict__ att2,
    const float* __restrict__ mask,
    float* __restrict__ rowmax, float* __restrict__ rowinv) {
  int row = blockIdx.x * 4 + (threadIdx.x >> 6);
  int lane = threadIdx.x & 63;
  int b = row >> 11;
  float a1r = att1[row];
  const float* a2 = att2 + b * M;
  const float* mk = mask + b * M;
  float mx = -1e30f;
#pragma unroll
  for (int i = 0; i < 8; ++i) {
    int m = (lane + i * 64) * 4;
    float4 av = *(const float4*)(a2 + m);
    float4 mv = *(const float4*)(mk + m);
    mx = fmaxf(mx, leaky_mask(a1r, av.x, mv.x));
    mx = fmaxf(mx, leaky_mask(a1r, av.y, mv.y));
    mx = fmaxf(mx, leaky_mask(a1r, av.z, mv.z));
    mx = fmaxf(mx, leaky_mask(a1r, av.w, mv.w));
  }
#pragma unroll
  for (int off = 32; off; off >>= 1) mx = fmaxf(mx, __shfl_xor(mx, off, 64));
  float sum = 0.f;
#pragma unroll
  for (int i = 0; i < 8; ++i) {
    int m = (lane + i * 64) * 4;
    float4 av = *(const float4*)(a2 + m);
    float4 mv = *(const float4*)(mk + m);
    sum += __expf(leaky_mask(a1r, av.x, mv.x) - mx);
    sum += __expf(leaky_mask(a1r, av.y, mv.y) - mx);
    sum += __expf(leaky_mask(a1r, av.z, mv.z) - mx);
    sum += __expf(leaky_mask(a1r, av.w, mv.w) - mx);
  }
#pragma unroll
  for (int off = 32; off; off >>= 1) sum += __shfl_xor(sum, off, 64);
  if (lane == 0) {
    rowmax[row] = mx;
    rowinv[row] = 1.f / sum;
  }
}

// ---------------------------------------------------------------------------
// K4 (fused probs + context) v3: BARRIER-FREE K-loop.
// 16 rows x 128 cols per block, 4 waves each own a contiguous 512-k chunk
// (4-way k-split). B fragments read DIRECTLY from global (L2-hot packed Wb,
// 16B/lane coalesced) — no LDS staging, no per-tile __syncthreads, so probs
// stores and B loads free-run. exp computed once per probs element, written
// in MFMA-A register layout (contiguous 128B/row per ks-step).
// End: 3-step LDS tree reduction of the 4 partial accumulators.
// LDS: scores region (16 KB) unioned with reduction scratch (18 KB).
// ---------------------------------------------------------------------------
__global__ __launch_bounds__(256, 4) void fused_kernel(
    const float* __restrict__ att1, const float* __restrict__ att2,
    const float* __restrict__ mask, const float* __restrict__ rowmax,
    const float* __restrict__ rowinv, const ushort* __restrict__ Wb,
    float* __restrict__ probs, float* __restrict__ ctx) {
  __shared__ float smem[2 * 64 * 36];  // 18 KB; scores during loop, red after
  float* att2s = smem;          // [0..2047]
  float* masks = smem + 2048;   // [2048..4095]

  int blk = blockIdx.x;         // 1024 blocks
  int b   = blk >> 7;           // 128 blocks per batch
  int rt  = blk & 127;
  int row0 = b * N + rt * 16;
  int t = threadIdx.x;
  int lane = t & 63;
  int w = t >> 6;
  int quad = lane >> 4;
  int l16 = lane & 15;

  // stage batch score vectors (16 KB, conflict-free b128)
#pragma unroll
  for (int i = 0; i < 2; ++i) {
    int idx = (t + i * 256) * 4;
    *(float4*)&att2s[idx] = *(const float4*)(att2 + b * M + idx);
    *(float4*)&masks[idx] = *(const float4*)(mask + b * M + idx);
  }
  __syncthreads();

  int myrow = row0 + l16;
  float a1v  = att1[myrow];
  float rmxL = rowmax[myrow];
  float rinL = rowinv[myrow];
  float* prow = probs + (size_t)myrow * M;
  const ushort* wbb = Wb + (size_t)b * M * E;  // packed batch slice

  f32x4 acc[8] = {};
  int kbase = w * 512;  // wave's contiguous k-chunk

  for (int ks = 0; ks < 512; ks += 32) {
    int kb = kbase + ks + quad * 8;
    // scores: b128 LDS reads, quads on disjoint bank groups, lanes broadcast
    float4 a0  = *(const float4*)&att2s[kb];
    float4 a1q = *(const float4*)&att2s[kb + 4];
    float4 m0  = *(const float4*)&masks[kb];
    float4 m1  = *(const float4*)&masks[kb + 4];
    float p[8];
    p[0] = __expf(leaky_mask(a1v, a0.x, m0.x) - rmxL) * rinL;
    p[1] = __expf(leaky_mask(a1v, a0.y, m0.y) - rmxL) * rinL;
    p[2] = __expf(leaky_mask(a1v, a0.z, m0.z) - rmxL) * rinL;
    p[3] = __expf(leaky_mask(a1v, a0.w, m0.w) - rmxL) * rinL;
    p[4] = __expf(leaky_mask(a1v, a1q.x, m1.x) - rmxL) * rinL;
    p[5] = __expf(leaky_mask(a1v, a1q.y, m1.y) - rmxL) * rinL;
    p[6] = __expf(leaky_mask(a1v, a1q.z, m1.z) - rmxL) * rinL;
    p[7] = __expf(leaky_mask(a1v, a1q.w, m1.w) - rmxL) * rinL;
    bf16x8 af;
#pragma unroll
    for (int j = 0; j < 8; ++j) af[j] = (short)f2bf(p[j]);
    *(float4*)(prow + kb)     = make_float4(p[0], p[1], p[2], p[3]);
    *(float4*)(prow + kb + 4) = make_float4(p[4], p[5], p[6], p[7]);
    const ushort* bptr = wbb + (size_t)(kb >> 3) * 1024;  // k-group row
#pragma unroll
    for (int cf = 0; cf < 8; ++cf) {
      bf16x8 bfb = *(const bf16x8*)(bptr + (cf * 16 + l16) * 8);
      acc[cf] =
          __builtin_amdgcn_mfma_f32_16x16x32_bf16(af, bfb, acc[cf], 0, 0, 0);
    }
  }

  // tree-reduce 4 partial accs (scores region is dead now; reuse as scratch)
  __syncthreads();
  float* red = smem;  // stride 36 floats per lane (16B aligned)
  if (w >= 2) {
    int base = (w - 2) * 64 * 36 + lane * 36;
#pragma unroll
    for (int cf = 0; cf < 8; ++cf) *(f32x4*)&red[base + cf * 4] = acc[cf];
  }
  __syncthreads();
  if (w < 2) {
    int base = w * 64 * 36 + lane * 36;
#pragma unroll
    for (int cf = 0; cf < 8; ++cf) {
      f32x4 o = *(const f32x4*)&red[base + cf * 4];
      acc[cf][0] += o[0]; acc[cf][1] += o[1];
      acc[cf][2] += o[2]; acc[cf][3] += o[3];
    }
  }
  __syncthreads();
  if (w == 1) {
    int base = lane * 36;
#pragma unroll
    for (int cf = 0; cf < 8; ++cf) *(f32x4*)&red[base + cf * 4] = acc[cf];
  }
  __syncthreads();
  if (w == 0) {
    int base = lane * 36;
#pragma unroll
    for (int cf = 0; cf < 8; ++cf) {
      f32x4 o = *(const f32x4*)&red[base + cf * 4];
      int nn = cf * 16 + l16;
#pragma unroll
      for (int reg = 0; reg < 4; ++reg) {
        int rr = row0 + quad * 4 + reg;
        ctx[(size_t)rr * E + nn] = acc[cf][reg] + o[reg];
      }
    }
  }
}

extern "C" void kernel_launch(void* const* d_in, const int* in_sizes, int n_in,
                              void* d_out, int out_size, void* d_ws,
                              size_t ws_size, hipStream_t stream) {
  (void)in_sizes; (void)n_in; (void)out_size; (void)ws_size;
  const float* in1  = (const float*)d_in[0];  // (B,N,DIN)
  const float* in2  = (const float*)d_in[1];  // (B,M,DIN)
  const float* mask = (const float*)d_in[2];  // (B,1,M)
  const float* W1   = (const float*)d_in[3];  // (DIN,E)
  const float* a1   = (const float*)d_in[4];  // (2E,1)

  float* ws     = (float*)d_ws;
  float* v1     = ws;                  // 256
  float* v2     = v1 + DIN;            // 256
  float* att1   = v2 + DIN;            // B*N
  float* att2   = att1 + B * N;        // B*M
  float* rowmax = att2 + B * M;        // B*N
  float* rowinv = rowmax + B * N;      // B*N
  ushort* Wb    = (ushort*)(rowinv + B * N);  // B*M*E bf16 packed (8.4 MB)

  float* ctx   = (float*)d_out;                 // B*N*E
  float* probs = ctx + (size_t)B * N * E;       // B*N*M

  hipLaunchKernelGGL(prep_v_kernel, dim3(1), dim3(256), 0, stream, W1, a1, v1, v2);
  hipLaunchKernelGGL(att_kernel, dim3((B * N + B * M) / 4), dim3(256), 0, stream,
                     in1, in2, v1, v2, att1, att2);
  hipLaunchKernelGGL(wh2_kernel, dim3(B * M / 32), dim3(256), 0, stream,
                     in2, W1, Wb);
  hipLaunchKernelGGL(stats_kernel, dim3(B * N / 4), dim3(256), 0, stream,
                     att1, att2, mask, rowmax, rowinv);
  hipLaunchKernelGGL(fused_kernel, dim3(B * N / 16), dim3(256), 0, stream,
                     att1, att2, mask, rowmax, rowinv, Wb, probs, ctx);
}